// Round 5
// baseline (40.167 us; speedup 1.0000x reference)
//
#include <hip/hip_runtime.h>
#include <math.h>

#define BATCH 4096
#define KMAX 50
#define DIM 256
#define BK 10   // gather batch depth per wave

__global__ __launch_bounds__(256) void kv_memory_kernel(
    const int* __restrict__ keys,          // B*K
    const int* __restrict__ values,        // B*K
    const int* __restrict__ pair_len,      // B
    const float* __restrict__ query,       // B*D
    const float* __restrict__ key_table,   // NUM_KEYS*D
    const float* __restrict__ value_table, // NUM_VALUES*D
    float* __restrict__ out)               // B*D
{
    const int lane = threadIdx.x & 63;
    const int wave = threadIdx.x >> 6;
    const int b    = blockIdx.x * 4 + wave;   // one wave = one batch row; no LDS, no barriers

    int len = pair_len[b];
    len = (len < 1) ? 1 : (len > KMAX ? KMAX : len);

    // Per-lane copy of this row's indices; lane k holds (keys[k], values[k]).
    const int li = (lane < KMAX) ? lane : (KMAX - 1);
    const int kk = keys[(size_t)b * KMAX + li];
    const int vv = values[(size_t)b * KMAX + li];

    // Lane owns dims [lane*4, lane*4+4)
    const float4 q = *reinterpret_cast<const float4*>(query + (size_t)b * DIM + lane * 4);

    // ---- Logits: batches of BK gathers, interleaved butterfly reductions ----
    float lg = -INFINITY;   // lanes >= len keep -inf
    #pragma unroll
    for (int kb = 0; kb < KMAX; kb += BK) {
        if (kb < len) {                      // wave-uniform
            float4 kr[BK];
            #pragma unroll
            for (int j = 0; j < BK; ++j) {
                const int k  = kb + j;
                const int kc = (k < len) ? k : (len - 1);   // clamp: keep loads unconditional
                const int idx = __shfl(kk, kc);
                kr[j] = *reinterpret_cast<const float4*>(
                    key_table + (size_t)idx * DIM + lane * 4);
            }
            float d[BK];
            #pragma unroll
            for (int j = 0; j < BK; ++j)
                d[j] = q.x * kr[j].x + q.y * kr[j].y + q.z * kr[j].z + q.w * kr[j].w;
            #pragma unroll
            for (int off = 32; off; off >>= 1) {
                #pragma unroll
                for (int j = 0; j < BK; ++j) d[j] += __shfl_xor(d[j], off);
            }
            #pragma unroll
            for (int j = 0; j < BK; ++j) {
                const int k = kb + j;
                if (k < len && lane == k) lg = d[j];
            }
        }
    }

    // ---- Softmax fully in-register (len >= 1 so m is finite) ----
    float m = lg;
    #pragma unroll
    for (int off = 32; off; off >>= 1) m = fmaxf(m, __shfl_xor(m, off));
    float e = __expf(lg - m);            // lg = -inf -> 0 for lanes >= len
    float s = e;
    #pragma unroll
    for (int off = 32; off; off >>= 1) s += __shfl_xor(s, off);
    const float p = e * (1.0f / s);

    // ---- Weighted value sum, same batched structure ----
    float4 acc = make_float4(0.f, 0.f, 0.f, 0.f);
    #pragma unroll
    for (int kb = 0; kb < KMAX; kb += BK) {
        if (kb < len) {                      // wave-uniform
            float4 vr[BK];
            float  w[BK];
            #pragma unroll
            for (int j = 0; j < BK; ++j) {
                const int k  = kb + j;
                const int kc = (k < len) ? k : (len - 1);
                const int idx = __shfl(vv, kc);
                vr[j] = *reinterpret_cast<const float4*>(
                    value_table + (size_t)idx * DIM + lane * 4);
                w[j] = (k < len) ? __shfl(p, k) : 0.0f;   // padded k contributes 0
            }
            #pragma unroll
            for (int j = 0; j < BK; ++j) {
                acc.x += w[j] * vr[j].x;
                acc.y += w[j] * vr[j].y;
                acc.z += w[j] * vr[j].z;
                acc.w += w[j] * vr[j].w;
            }
        }
    }

    *reinterpret_cast<float4*>(out + (size_t)b * DIM + lane * 4) = acc;
}

extern "C" void kernel_launch(void* const* d_in, const int* in_sizes, int n_in,
                              void* d_out, int out_size, void* d_ws, size_t ws_size,
                              hipStream_t stream) {
    const int*   keys        = (const int*)d_in[0];
    const int*   values      = (const int*)d_in[1];
    const int*   pair_len    = (const int*)d_in[2];
    const float* query       = (const float*)d_in[3];
    const float* key_table   = (const float*)d_in[4];
    const float* value_table = (const float*)d_in[5];
    float* out = (float*)d_out;

    kv_memory_kernel<<<BATCH / 4, 256, 0, stream>>>(
        keys, values, pair_len, query, key_table, value_table, out);
}